// Round 4
// baseline (407.957 us; speedup 1.0000x reference)
//
#include <hip/hip_runtime.h>

#define NNODE 50000
#define NEDGE 800000

typedef __attribute__((ext_vector_type(8))) short bf16x8;
typedef __attribute__((ext_vector_type(4))) float f32x4;

// workspace byte offsets
#define WB_QCB   0          // 64*64 bf16   qc + all folded biases (natural cols)
#define WB_WRTB  8192       // 64*64 bf16   (Wr@W1r)^T [n][k], natural k
#define WB_W2SB  16384      // 128*64 bf16  W2^T [n][perm k], XOR-granule swizzled
#define WB_WEH   32768      // 64*64 fp32   We@W1h
#define WB_WET   49152      // 64*64 fp32   We@W1t
#define WB_NHB   65536      // 50000*64 bf16 (natural cols)
#define WB_NTB   6465536    // 50000*64 bf16
#define WB_EIDX  12865536   // 800000 * int4 {head, tail, qid, 0}

__device__ inline ushort f2b(float x) {           // fp32 -> bf16 RNE
    uint u = __float_as_uint(x);
    return (ushort)((u + 0x7fffu + ((u >> 16) & 1u)) >> 16);
}
// two fp32 -> packed bf16x2 via v_perm (RNE)
__device__ inline uint pack2(float lo, float hi) {
    uint a = __float_as_uint(lo);
    uint b = __float_as_uint(hi);
    a += 0x7fffu + ((a >> 16) & 1u);
    b += 0x7fffu + ((b >> 16) & 1u);
    return __builtin_amdgcn_perm(b, a, 0x07060302);
}
__device__ inline float bLo(uint u) { return __uint_as_float(u << 16); }
__device__ inline float bHi(uint u) { return __uint_as_float(u & 0xffff0000u); }

__device__ inline float row16_reduce(float v) {   // sum over 16-lane row via DPP
    int x;
    x = __builtin_amdgcn_mov_dpp(__float_as_int(v), 0x121, 0xf, 0xf, false); v += __int_as_float(x);
    x = __builtin_amdgcn_mov_dpp(__float_as_int(v), 0x122, 0xf, 0xf, false); v += __int_as_float(x);
    x = __builtin_amdgcn_mov_dpp(__float_as_int(v), 0x124, 0xf, 0xf, false); v += __int_as_float(x);
    x = __builtin_amdgcn_mov_dpp(__float_as_int(v), 0x128, 0xf, 0xf, false); v += __int_as_float(x);
    return v;
}

union B8U { uint4 u; bf16x8 b; };

__device__ inline void stage64(float* dst, const float* __restrict__ src, int t) {
    #pragma unroll
    for (int i = 0; i < 4; ++i) {
        int f = t + i * 256;
        *(float4*)&dst[f * 4] = *(const float4*)&src[f * 4];
    }
}

__device__ inline void gemm64(const float* sA, const float* sB, int t, float acc[4][4]) {
    const int r0 = (t >> 4) * 4, c0 = (t & 15) * 4;
    #pragma unroll
    for (int j = 0; j < 4; ++j)
        #pragma unroll
        for (int i = 0; i < 4; ++i) acc[j][i] = 0.f;
    #pragma unroll 4
    for (int k = 0; k < 64; ++k) {
        float4 b = *(const float4*)&sB[k * 64 + c0];
        float bv[4] = {b.x, b.y, b.z, b.w};
        #pragma unroll
        for (int j = 0; j < 4; ++j) {
            float a = sA[(r0 + j) * 64 + k];
            #pragma unroll
            for (int i = 0; i < 4; ++i) acc[j][i] = fmaf(a, bv[i], acc[j][i]);
        }
    }
}

// blocks 0..4: small weight folds; blocks 5..786: eidx build (1024 edges each)
__global__ __launch_bounds__(256)
void prep_a(const float* __restrict__ Q,
            const float* __restrict__ Wq, const float* __restrict__ bq,
            const float* __restrict__ We, const float* __restrict__ be,
            const float* __restrict__ Wr, const float* __restrict__ br,
            const float* __restrict__ W1, const float* __restrict__ b1,
            const float* __restrict__ W2,
            const int* __restrict__ EI, const int* __restrict__ NB,
            char* __restrict__ wsb)
{
    __shared__ float sA[4096], sB[4096], sC[4096], sBias[64];
    const int t = threadIdx.x;
    const int bid = blockIdx.x;
    const int r0 = (t >> 4) * 4, c0 = (t & 15) * 4;

    if (bid >= 5) {
        // ---- eidx build ----
        int e0 = (bid - 5) * 1024 + t * 4;
        if (e0 < NEDGE) {
            int4 hds = *(const int4*)&EI[e0];
            int4 tls = *(const int4*)&EI[NEDGE + e0];
            int4* eidx = (int4*)(wsb + WB_EIDX);
            eidx[e0 + 0] = make_int4(hds.x, tls.x, NB[hds.x], 0);
            eidx[e0 + 1] = make_int4(hds.y, tls.y, NB[hds.y], 0);
            eidx[e0 + 2] = make_int4(hds.z, tls.z, NB[hds.z], 0);
            eidx[e0 + 3] = make_int4(hds.w, tls.w, NB[hds.w], 0);
        }
        return;
    }

    if (bid == 0) {
        // qc = Q @ (Wq@W1q) + (b1 + bq@W1q + be@(W1h+W1t) + br@W1r)
        stage64(sA, Wq, t); stage64(sB, W1, t);
        __syncthreads();
        float acc[4][4];
        gemm64(sA, sB, t, acc);
        #pragma unroll
        for (int j = 0; j < 4; ++j)
            *(float4*)&sC[(r0 + j) * 64 + c0] = make_float4(acc[j][0], acc[j][1], acc[j][2], acc[j][3]);
        if (t < 64) {
            float s = b1[t];
            for (int k = 0; k < 64; ++k) {
                s = fmaf(bq[k], W1[k * 64 + t], s);
                s = fmaf(be[k], W1[(64 + k) * 64 + t] + W1[(192 + k) * 64 + t], s);
                s = fmaf(br[k], W1[(128 + k) * 64 + t], s);
            }
            sBias[t] = s;
        }
        __syncthreads();
        stage64(sA, Q, t);
        __syncthreads();
        gemm64(sA, sC, t, acc);
        ushort* qcb = (ushort*)(wsb + WB_QCB);
        #pragma unroll
        for (int j = 0; j < 4; ++j) {
            ushort4 p;
            p.x = f2b(acc[j][0] + sBias[c0 + 0]);
            p.y = f2b(acc[j][1] + sBias[c0 + 1]);
            p.z = f2b(acc[j][2] + sBias[c0 + 2]);
            p.w = f2b(acc[j][3] + sBias[c0 + 3]);
            *(ushort4*)&qcb[(r0 + j) * 64 + c0] = p;
        }
    } else if (bid == 1 || bid == 2) {
        const float* w1seg = W1 + (bid == 1 ? 64 * 64 : 192 * 64);
        float* dst = (float*)(wsb + (bid == 1 ? WB_WEH : WB_WET));
        stage64(sA, We, t); stage64(sB, w1seg, t);
        __syncthreads();
        float acc[4][4];
        gemm64(sA, sB, t, acc);
        #pragma unroll
        for (int j = 0; j < 4; ++j)
            *(float4*)&dst[(r0 + j) * 64 + c0] = make_float4(acc[j][0], acc[j][1], acc[j][2], acc[j][3]);
    } else if (bid == 3) {
        stage64(sA, Wr, t); stage64(sB, W1 + 128 * 64, t);
        __syncthreads();
        float acc[4][4];
        gemm64(sA, sB, t, acc);
        ushort* wrtb = (ushort*)(wsb + WB_WRTB);
        #pragma unroll
        for (int j = 0; j < 4; ++j)
            #pragma unroll
            for (int i = 0; i < 4; ++i)
                wrtb[(c0 + i) * 64 + (r0 + j)] = f2b(acc[j][i]);
    } else {
        // W2^T bf16, K-permuted p(k)=(k&15)*4+(k>>4), then XOR-granule swizzle:
        // phys hw index = n*64 + ((p>>3) ^ (n&7))*8 + (p&7)
        ushort* w2s = (ushort*)(wsb + WB_W2SB);
        #pragma unroll
        for (int i = 0; i < 32; ++i) {
            int f = t + i * 256;           // f < 8192
            int k = f >> 7, n = f & 127;
            int p = (k & 15) * 4 + (k >> 4);
            w2s[n * 64 + (((p >> 3) ^ (n & 7)) * 8) + (p & 7)] = f2b(W2[f]);
        }
    }
}

__global__ __launch_bounds__(256)
void prep_nodes(const float* __restrict__ Xn, const char* __restrict__ wsb_c,
                char* __restrict__ wsb)
{
    __shared__ float sXT[64 * 68];
    __shared__ float sWeh[4096], sWet[4096];
    const int t = threadIdx.x;
    const int nbase = blockIdx.x * 64;
    const float* Weh = (const float*)(wsb_c + WB_WEH);
    const float* Wet = (const float*)(wsb_c + WB_WET);
    ushort* nhb = (ushort*)(wsb + WB_NHB);
    ushort* ntb = (ushort*)(wsb + WB_NTB);

    #pragma unroll
    for (int i = 0; i < 4; ++i) {
        int f = t + i * 256;
        int n = f >> 4, s4 = (f & 15) * 4;
        int gn = nbase + n;
        float4 v = make_float4(0.f, 0.f, 0.f, 0.f);
        if (gn < NNODE) v = *(const float4*)&Xn[gn * 64 + s4];
        sXT[(s4 + 0) * 68 + n] = v.x;
        sXT[(s4 + 1) * 68 + n] = v.y;
        sXT[(s4 + 2) * 68 + n] = v.z;
        sXT[(s4 + 3) * 68 + n] = v.w;
    }
    #pragma unroll
    for (int i = 0; i < 4; ++i) {
        int f = t + i * 256;
        *(float4*)&sWeh[f * 4] = *(const float4*)&Weh[f * 4];
        *(float4*)&sWet[f * 4] = *(const float4*)&Wet[f * 4];
    }
    __syncthreads();

    const int er = (t >> 4) * 4, cc = (t & 15) * 4;
    float ah[4][4], at[4][4];
    #pragma unroll
    for (int j = 0; j < 4; ++j)
        #pragma unroll
        for (int i = 0; i < 4; ++i) { ah[j][i] = 0.f; at[j][i] = 0.f; }
    #pragma unroll 4
    for (int k = 0; k < 64; ++k) {
        float4 a  = *(const float4*)&sXT[k * 68 + er];
        float4 bh = *(const float4*)&sWeh[k * 64 + cc];
        float4 bt = *(const float4*)&sWet[k * 64 + cc];
        float av[4] = {a.x, a.y, a.z, a.w};
        #pragma unroll
        for (int j = 0; j < 4; ++j) {
            ah[j][0] = fmaf(av[j], bh.x, ah[j][0]); ah[j][1] = fmaf(av[j], bh.y, ah[j][1]);
            ah[j][2] = fmaf(av[j], bh.z, ah[j][2]); ah[j][3] = fmaf(av[j], bh.w, ah[j][3]);
            at[j][0] = fmaf(av[j], bt.x, at[j][0]); at[j][1] = fmaf(av[j], bt.y, at[j][1]);
            at[j][2] = fmaf(av[j], bt.z, at[j][2]); at[j][3] = fmaf(av[j], bt.w, at[j][3]);
        }
    }
    #pragma unroll
    for (int j = 0; j < 4; ++j) {
        int n = nbase + er + j;
        if (n < NNODE) {
            ushort4 ph, pt;
            ph.x = f2b(ah[j][0]); ph.y = f2b(ah[j][1]); ph.z = f2b(ah[j][2]); ph.w = f2b(ah[j][3]);
            pt.x = f2b(at[j][0]); pt.y = f2b(at[j][1]); pt.z = f2b(at[j][2]); pt.w = f2b(at[j][3]);
            *(ushort4*)&nhb[n * 64 + cc] = ph;
            *(ushort4*)&ntb[n * 64 + cc] = pt;
        }
    }
}

__global__ __launch_bounds__(256, 6)
void edge_kernel(const float* __restrict__ Xe,
                 const float* __restrict__ b2,
                 const float* __restrict__ Wh,
                 const float* __restrict__ bh,
                 const char* __restrict__ wsb,
                 float* __restrict__ out)
{
    __shared__ ushort sW2[128 * 64];   // 16 KB, XOR-granule swizzled, flat stride 64
    __shared__ ushort sG[64 * 72];     // 9 KB, gather sums then H1 in place (perm cols)
    __shared__ float  sB2s[128], sWhs[128];

    const int t = threadIdx.x;
    const int ebase = blockIdx.x * 64;
    const int l = t & 63, w = t >> 6;
    const int m = l & 15, qq = l >> 4, q8 = qq * 8;

    const ushort* qcb  = (const ushort*)(wsb + WB_QCB);
    const ushort* wrtb = (const ushort*)(wsb + WB_WRTB);
    const ushort* w2s  = (const ushort*)(wsb + WB_W2SB);
    const ushort* nhb  = (const ushort*)(wsb + WB_NHB);
    const ushort* ntb  = (const ushort*)(wsb + WB_NTB);
    const int4*   eidx = (const int4*)(wsb + WB_EIDX);

    // ---- one-shot index load (no dependent chain) ----
    const int eg = w * 16 + (l >> 2);
    const int qg = l & 3;
    int4 idx = eidx[ebase + eg];

    // ---- X A-fragment loads (row w*16+m) ----
    const float* xrow = &Xe[(size_t)(ebase + w * 16 + m) * 64];
    float4 x0 = *(const float4*)&xrow[q8];
    float4 x1 = *(const float4*)&xrow[q8 + 4];
    float4 x2 = *(const float4*)&xrow[32 + q8];
    float4 x3 = *(const float4*)&xrow[32 + q8 + 4];

    // ---- stage W2 (pre-swizzled: straight b128 copy) ----
    #pragma unroll
    for (int i = 0; i < 4; ++i) {
        int f = t + i * 256;
        *(uint4*)&sW2[f * 8] = *(const uint4*)&w2s[f * 8];
    }
    if (t < 128) { sB2s[t] = b2[t]; sWhs[t] = Wh[t]; }
    float bh0 = bh[0];

    // ---- gathers (independent now that qid is precomputed) ----
    {
        const int hd = idx.x, tl = idx.y, qi = idx.z;
        float s[16];
        #pragma unroll
        for (int a = 0; a < 4; ++a) {
            int coff = a * 16 + qg * 4;
            uint2 gq = *(const uint2*)&qcb[qi * 64 + coff];
            uint2 gh = *(const uint2*)&nhb[(size_t)hd * 64 + coff];
            uint2 gt = *(const uint2*)&ntb[(size_t)tl * 64 + coff];
            s[a]      = bLo(gq.x) + bLo(gh.x) + bLo(gt.x);
            s[4 + a]  = bHi(gq.x) + bHi(gh.x) + bHi(gt.x);
            s[8 + a]  = bLo(gq.y) + bLo(gh.y) + bLo(gt.y);
            s[12 + a] = bHi(gq.y) + bHi(gh.y) + bHi(gt.y);
        }
        uint pk[8];
        #pragma unroll
        for (int wd = 0; wd < 8; ++wd) pk[wd] = pack2(s[2 * wd], s[2 * wd + 1]);
        *(uint4*)&sG[eg * 72 + qg * 16]     = make_uint4(pk[0], pk[1], pk[2], pk[3]);
        *(uint4*)&sG[eg * 72 + qg * 16 + 8] = make_uint4(pk[4], pk[5], pk[6], pk[7]);
    }

    // ---- pack X A-fragments (registers only) ----
    B8U a0, a1;
    a0.u = make_uint4(pack2(x0.x, x0.y), pack2(x0.z, x0.w),
                      pack2(x1.x, x1.y), pack2(x1.z, x1.w));
    a1.u = make_uint4(pack2(x2.x, x2.y), pack2(x2.z, x2.w),
                      pack2(x3.x, x3.y), pack2(x3.z, x3.w));

    __syncthreads();   // protects sW2 / biases only; sG is wave-local

    // ---- h1 = X @ Wr' (B-frags straight from global; L1/L2-hot 8 KB table) ----
    f32x4 acc1[4];
    #pragma unroll
    for (int nt = 0; nt < 4; ++nt) {
        const ushort* row = &wrtb[(nt * 16 + m) * 64];
        B8U b0, b1v;
        b0.u  = *(const uint4*)&row[q8];
        b1v.u = *(const uint4*)&row[32 + q8];
        f32x4 c = {0.f, 0.f, 0.f, 0.f};
        c = __builtin_amdgcn_mfma_f32_16x16x32_bf16(a0.b, b0.b, c, 0, 0, 0);
        c = __builtin_amdgcn_mfma_f32_16x16x32_bf16(a1.b, b1v.b, c, 0, 0, 0);
        acc1[nt] = c;
    }

    // ---- epilogue: + gather, relu, H1 written back IN PLACE (b64 vec ops) ----
    #pragma unroll
    for (int r = 0; r < 4; ++r) {
        int e = w * 16 + qq * 4 + r;
        uint2 gg = *(const uint2*)&sG[e * 72 + m * 4];
        uint lo = pack2(fmaxf(acc1[0][r] + bLo(gg.x), 0.f),
                        fmaxf(acc1[1][r] + bHi(gg.x), 0.f));
        uint hi = pack2(fmaxf(acc1[2][r] + bLo(gg.y), 0.f),
                        fmaxf(acc1[3][r] + bHi(gg.y), 0.f));
        *(uint2*)&sG[e * 72 + m * 4] = make_uint2(lo, hi);
    }

    // ---- h2 = relu(H1@W2 + b2); logit = h2@Wh + bh ----
    bf16x8 A0 = *(const bf16x8*)&sG[(w * 16 + m) * 72 + q8];
    bf16x8 A1 = *(const bf16x8*)&sG[(w * 16 + m) * 72 + 32 + q8];
    const int o1 = (qq ^ (m & 7)) * 8;
    const int o2 = o1 ^ 32;
    float part[4] = {0.f, 0.f, 0.f, 0.f};
    #pragma unroll
    for (int nt = 0; nt < 8; ++nt) {
        B8U B0, B1;
        B0.u = *(const uint4*)&sW2[nt * 1024 + m * 64 + o1];
        B1.u = *(const uint4*)&sW2[nt * 1024 + m * 64 + o2];
        f32x4 c = {0.f, 0.f, 0.f, 0.f};
        c = __builtin_amdgcn_mfma_f32_16x16x32_bf16(A0, B0.b, c, 0, 0, 0);
        c = __builtin_amdgcn_mfma_f32_16x16x32_bf16(A1, B1.b, c, 0, 0, 0);
        int col = nt * 16 + m;
        float b2v = sB2s[col], whv = sWhs[col];
        #pragma unroll
        for (int r = 0; r < 4; ++r)
            part[r] = fmaf(fmaxf(c[r] + b2v, 0.f), whv, part[r]);
    }

    // ---- 16-lane reduction on the VALU pipe (DPP row_ror) ----
    part[0] = row16_reduce(part[0]);
    part[1] = row16_reduce(part[1]);
    part[2] = row16_reduce(part[2]);
    part[3] = row16_reduce(part[3]);

    if (m == 0) {
        float4 o;
        o.x = 1.f / (1.f + __expf(-(part[0] + bh0)));
        o.y = 1.f / (1.f + __expf(-(part[1] + bh0)));
        o.z = 1.f / (1.f + __expf(-(part[2] + bh0)));
        o.w = 1.f / (1.f + __expf(-(part[3] + bh0)));
        *(float4*)&out[ebase + w * 16 + qq * 4] = o;
    }
}

extern "C" void kernel_launch(void* const* d_in, const int* in_sizes, int n_in,
                              void* d_out, int out_size, void* d_ws, size_t ws_size,
                              hipStream_t stream)
{
    const float* Q   = (const float*)d_in[0];
    const float* Xn  = (const float*)d_in[1];
    const float* Xe  = (const float*)d_in[2];
    const int*   EI  = (const int*)d_in[3];
    const int*   NB  = (const int*)d_in[4];
    const float* Wq  = (const float*)d_in[5];
    const float* bq  = (const float*)d_in[6];
    const float* We  = (const float*)d_in[7];
    const float* be  = (const float*)d_in[8];
    const float* Wr  = (const float*)d_in[9];
    const float* br  = (const float*)d_in[10];
    const float* W1  = (const float*)d_in[11];
    const float* b1  = (const float*)d_in[12];
    const float* W2  = (const float*)d_in[13];
    const float* b2  = (const float*)d_in[14];
    const float* Wh  = (const float*)d_in[15];
    const float* bh  = (const float*)d_in[16];
    float* out = (float*)d_out;
    char*  wsb = (char*)d_ws;

    prep_a<<<5 + (NEDGE + 1023) / 1024, 256, 0, stream>>>(
        Q, Wq, bq, We, be, Wr, br, W1, b1, W2, EI, NB, wsb);
    prep_nodes<<<(NNODE + 63) / 64, 256, 0, stream>>>(Xn, wsb, wsb);
    edge_kernel<<<NEDGE / 64, 256, 0, stream>>>(Xe, b2, Wh, bh, wsb, out);
}

// Round 5
// 394.462 us; speedup vs baseline: 1.0342x; 1.0342x over previous
//
#include <hip/hip_runtime.h>

#define NNODE 50000
#define NEDGE 800000

typedef __attribute__((ext_vector_type(8))) short bf16x8;
typedef __attribute__((ext_vector_type(4))) float f32x4;

// workspace byte offsets
#define WB_QCB   0          // 64*64 bf16   qc + all folded biases (natural cols)
#define WB_WRTB  8192       // 64*64 bf16   (Wr@W1r)^T [n][k], natural k
#define WB_W2SB  16384      // 128*64 bf16  W2^T [n][perm k], XOR-granule swizzled
#define WB_WEH   32768      // 64*64 fp32   We@W1h
#define WB_WET   49152      // 64*64 fp32   We@W1t
#define WB_NHB   65536      // 50000*64 bf16 (natural cols)
#define WB_NTB   6465536    // 50000*64 bf16
#define WB_EIDX  12865536   // 800000 * int4 {head, tail, qid, 0}

__device__ inline ushort f2b(float x) {           // fp32 -> bf16 RNE
    uint u = __float_as_uint(x);
    return (ushort)((u + 0x7fffu + ((u >> 16) & 1u)) >> 16);
}
// two fp32 -> packed bf16x2 via v_perm (RNE)
__device__ inline uint pack2(float lo, float hi) {
    uint a = __float_as_uint(lo);
    uint b = __float_as_uint(hi);
    a += 0x7fffu + ((a >> 16) & 1u);
    b += 0x7fffu + ((b >> 16) & 1u);
    return __builtin_amdgcn_perm(b, a, 0x07060302);
}

__device__ inline float row16_reduce(float v) {   // sum over 16-lane row via DPP
    int x;
    x = __builtin_amdgcn_mov_dpp(__float_as_int(v), 0x121, 0xf, 0xf, false); v += __int_as_float(x);
    x = __builtin_amdgcn_mov_dpp(__float_as_int(v), 0x122, 0xf, 0xf, false); v += __int_as_float(x);
    x = __builtin_amdgcn_mov_dpp(__float_as_int(v), 0x124, 0xf, 0xf, false); v += __int_as_float(x);
    x = __builtin_amdgcn_mov_dpp(__float_as_int(v), 0x128, 0xf, 0xf, false); v += __int_as_float(x);
    return v;
}

union B8U { uint4 u; bf16x8 b; };

__device__ inline void stage64(float* dst, const float* __restrict__ src, int t) {
    #pragma unroll
    for (int i = 0; i < 4; ++i) {
        int f = t + i * 256;
        *(float4*)&dst[f * 4] = *(const float4*)&src[f * 4];
    }
}

__device__ inline void gemm64(const float* sA, const float* sB, int t, float acc[4][4]) {
    const int r0 = (t >> 4) * 4, c0 = (t & 15) * 4;
    #pragma unroll
    for (int j = 0; j < 4; ++j)
        #pragma unroll
        for (int i = 0; i < 4; ++i) acc[j][i] = 0.f;
    #pragma unroll 4
    for (int k = 0; k < 64; ++k) {
        float4 b = *(const float4*)&sB[k * 64 + c0];
        float bv[4] = {b.x, b.y, b.z, b.w};
        #pragma unroll
        for (int j = 0; j < 4; ++j) {
            float a = sA[(r0 + j) * 64 + k];
            #pragma unroll
            for (int i = 0; i < 4; ++i) acc[j][i] = fmaf(a, bv[i], acc[j][i]);
        }
    }
}

// blocks 0..4: small weight folds; blocks 5..786: eidx build (1024 edges each)
__global__ __launch_bounds__(256)
void prep_a(const float* __restrict__ Q,
            const float* __restrict__ Wq, const float* __restrict__ bq,
            const float* __restrict__ We, const float* __restrict__ be,
            const float* __restrict__ Wr, const float* __restrict__ br,
            const float* __restrict__ W1, const float* __restrict__ b1,
            const float* __restrict__ W2,
            const int* __restrict__ EI, const int* __restrict__ NB,
            char* __restrict__ wsb)
{
    __shared__ float sA[4096], sB[4096], sC[4096], sBias[64];
    const int t = threadIdx.x;
    const int bid = blockIdx.x;
    const int r0 = (t >> 4) * 4, c0 = (t & 15) * 4;

    if (bid >= 5) {
        int e0 = (bid - 5) * 1024 + t * 4;
        if (e0 < NEDGE) {
            int4 hds = *(const int4*)&EI[e0];
            int4 tls = *(const int4*)&EI[NEDGE + e0];
            int4* eidx = (int4*)(wsb + WB_EIDX);
            eidx[e0 + 0] = make_int4(hds.x, tls.x, NB[hds.x], 0);
            eidx[e0 + 1] = make_int4(hds.y, tls.y, NB[hds.y], 0);
            eidx[e0 + 2] = make_int4(hds.z, tls.z, NB[hds.z], 0);
            eidx[e0 + 3] = make_int4(hds.w, tls.w, NB[hds.w], 0);
        }
        return;
    }

    if (bid == 0) {
        // qc = Q @ (Wq@W1q) + (b1 + bq@W1q + be@(W1h+W1t) + br@W1r)
        stage64(sA, Wq, t); stage64(sB, W1, t);
        __syncthreads();
        float acc[4][4];
        gemm64(sA, sB, t, acc);
        #pragma unroll
        for (int j = 0; j < 4; ++j)
            *(float4*)&sC[(r0 + j) * 64 + c0] = make_float4(acc[j][0], acc[j][1], acc[j][2], acc[j][3]);
        if (t < 64) {
            float s = b1[t];
            for (int k = 0; k < 64; ++k) {
                s = fmaf(bq[k], W1[k * 64 + t], s);
                s = fmaf(be[k], W1[(64 + k) * 64 + t] + W1[(192 + k) * 64 + t], s);
                s = fmaf(br[k], W1[(128 + k) * 64 + t], s);
            }
            sBias[t] = s;
        }
        __syncthreads();
        stage64(sA, Q, t);
        __syncthreads();
        gemm64(sA, sC, t, acc);
        ushort* qcb = (ushort*)(wsb + WB_QCB);
        #pragma unroll
        for (int j = 0; j < 4; ++j) {
            ushort4 p;
            p.x = f2b(acc[j][0] + sBias[c0 + 0]);
            p.y = f2b(acc[j][1] + sBias[c0 + 1]);
            p.z = f2b(acc[j][2] + sBias[c0 + 2]);
            p.w = f2b(acc[j][3] + sBias[c0 + 3]);
            *(ushort4*)&qcb[(r0 + j) * 64 + c0] = p;
        }
    } else if (bid == 1 || bid == 2) {
        const float* w1seg = W1 + (bid == 1 ? 64 * 64 : 192 * 64);
        float* dst = (float*)(wsb + (bid == 1 ? WB_WEH : WB_WET));
        stage64(sA, We, t); stage64(sB, w1seg, t);
        __syncthreads();
        float acc[4][4];
        gemm64(sA, sB, t, acc);
        #pragma unroll
        for (int j = 0; j < 4; ++j)
            *(float4*)&dst[(r0 + j) * 64 + c0] = make_float4(acc[j][0], acc[j][1], acc[j][2], acc[j][3]);
    } else if (bid == 3) {
        stage64(sA, Wr, t); stage64(sB, W1 + 128 * 64, t);
        __syncthreads();
        float acc[4][4];
        gemm64(sA, sB, t, acc);
        ushort* wrtb = (ushort*)(wsb + WB_WRTB);
        #pragma unroll
        for (int j = 0; j < 4; ++j)
            #pragma unroll
            for (int i = 0; i < 4; ++i)
                wrtb[(c0 + i) * 64 + (r0 + j)] = f2b(acc[j][i]);
    } else {
        // W2^T bf16, K-permuted p(k)=(k&15)*4+(k>>4), then XOR-granule swizzle:
        // phys hw index = n*64 + ((p>>3) ^ (n&7))*8 + (p&7)
        ushort* w2s = (ushort*)(wsb + WB_W2SB);
        #pragma unroll
        for (int i = 0; i < 32; ++i) {
            int f = t + i * 256;           // f < 8192
            int k = f >> 7, n = f & 127;
            int p = (k & 15) * 4 + (k >> 4);
            w2s[n * 64 + (((p >> 3) ^ (n & 7)) * 8) + (p & 7)] = f2b(W2[f]);
        }
    }
}

__global__ __launch_bounds__(256)
void prep_nodes(const float* __restrict__ Xn, const char* __restrict__ wsb_c,
                char* __restrict__ wsb)
{
    __shared__ float sXT[64 * 68];
    __shared__ float sWeh[4096], sWet[4096];
    const int t = threadIdx.x;
    const int nbase = blockIdx.x * 64;
    const float* Weh = (const float*)(wsb_c + WB_WEH);
    const float* Wet = (const float*)(wsb_c + WB_WET);
    ushort* nhb = (ushort*)(wsb + WB_NHB);
    ushort* ntb = (ushort*)(wsb + WB_NTB);

    #pragma unroll
    for (int i = 0; i < 4; ++i) {
        int f = t + i * 256;
        int n = f >> 4, s4 = (f & 15) * 4;
        int gn = nbase + n;
        float4 v = make_float4(0.f, 0.f, 0.f, 0.f);
        if (gn < NNODE) v = *(const float4*)&Xn[gn * 64 + s4];
        sXT[(s4 + 0) * 68 + n] = v.x;
        sXT[(s4 + 1) * 68 + n] = v.y;
        sXT[(s4 + 2) * 68 + n] = v.z;
        sXT[(s4 + 3) * 68 + n] = v.w;
    }
    #pragma unroll
    for (int i = 0; i < 4; ++i) {
        int f = t + i * 256;
        *(float4*)&sWeh[f * 4] = *(const float4*)&Weh[f * 4];
        *(float4*)&sWet[f * 4] = *(const float4*)&Wet[f * 4];
    }
    __syncthreads();

    const int er = (t >> 4) * 4, cc = (t & 15) * 4;
    float ah[4][4], at[4][4];
    #pragma unroll
    for (int j = 0; j < 4; ++j)
        #pragma unroll
        for (int i = 0; i < 4; ++i) { ah[j][i] = 0.f; at[j][i] = 0.f; }
    #pragma unroll 4
    for (int k = 0; k < 64; ++k) {
        float4 a  = *(const float4*)&sXT[k * 68 + er];
        float4 bh = *(const float4*)&sWeh[k * 64 + cc];
        float4 bt = *(const float4*)&sWet[k * 64 + cc];
        float av[4] = {a.x, a.y, a.z, a.w};
        #pragma unroll
        for (int j = 0; j < 4; ++j) {
            ah[j][0] = fmaf(av[j], bh.x, ah[j][0]); ah[j][1] = fmaf(av[j], bh.y, ah[j][1]);
            ah[j][2] = fmaf(av[j], bh.z, ah[j][2]); ah[j][3] = fmaf(av[j], bh.w, ah[j][3]);
            at[j][0] = fmaf(av[j], bt.x, at[j][0]); at[j][1] = fmaf(av[j], bt.y, at[j][1]);
            at[j][2] = fmaf(av[j], bt.z, at[j][2]); at[j][3] = fmaf(av[j], bt.w, at[j][3]);
        }
    }
    #pragma unroll
    for (int j = 0; j < 4; ++j) {
        int n = nbase + er + j;
        if (n < NNODE) {
            ushort4 ph, pt;
            ph.x = f2b(ah[j][0]); ph.y = f2b(ah[j][1]); ph.z = f2b(ah[j][2]); ph.w = f2b(ah[j][3]);
            pt.x = f2b(at[j][0]); pt.y = f2b(at[j][1]); pt.z = f2b(at[j][2]); pt.w = f2b(at[j][3]);
            *(ushort4*)&nhb[n * 64 + cc] = ph;
            *(ushort4*)&ntb[n * 64 + cc] = pt;
        }
    }
}

__global__ __launch_bounds__(256, 4)
void edge_kernel(const float* __restrict__ Xe,
                 const float* __restrict__ b2,
                 const float* __restrict__ Wh,
                 const float* __restrict__ bh,
                 const char* __restrict__ wsb,
                 float* __restrict__ out)
{
    __shared__ ushort sW2[128 * 64];   // 16 KB, XOR-granule swizzled, flat stride 64
    __shared__ ushort sH[64 * 72];     // 9 KB, H1 bf16 (perm cols), wave-local rows
    __shared__ float  sB2s[128], sWhs[128];

    const int t = threadIdx.x;
    const int ebase = blockIdx.x * 64;
    const int l = t & 63, w = t >> 6;
    const int m = l & 15, qq = l >> 4, q8 = qq * 8;

    const ushort* qcb  = (const ushort*)(wsb + WB_QCB);
    const ushort* wrtb = (const ushort*)(wsb + WB_WRTB);
    const ushort* w2s  = (const ushort*)(wsb + WB_W2SB);
    const ushort* nhb  = (const ushort*)(wsb + WB_NHB);
    const ushort* ntb  = (const ushort*)(wsb + WB_NTB);
    const int4*   eidx = (const int4*)(wsb + WB_EIDX);

    // ---- this lane's edge (A-fragment row): e = ebase + w*16 + m ----
    const int erow = w * 16 + m;
    int4 idx = eidx[ebase + erow];     // 4 lanes (same m) broadcast

    // ---- X A-fragment loads ----
    const float* xrow = &Xe[(size_t)(ebase + erow) * 64];
    float4 x0 = *(const float4*)&xrow[q8];
    float4 x1 = *(const float4*)&xrow[q8 + 4];
    float4 x2 = *(const float4*)&xrow[32 + q8];
    float4 x3 = *(const float4*)&xrow[32 + q8 + 4];

    // ---- gather A-fragments: 6 wide b128 loads (qc / nh / nt, two K-halves) ----
    const ushort* qrow = &qcb[(size_t)idx.z * 64];
    const ushort* hrow = &nhb[(size_t)idx.x * 64];
    const ushort* trow = &ntb[(size_t)idx.y * 64];
    B8U gq0, gq1, gh0, gh1, gt0, gt1;
    gq0.u = *(const uint4*)&qrow[q8];      gq1.u = *(const uint4*)&qrow[32 + q8];
    gh0.u = *(const uint4*)&hrow[q8];      gh1.u = *(const uint4*)&hrow[32 + q8];
    gt0.u = *(const uint4*)&trow[q8];      gt1.u = *(const uint4*)&trow[32 + q8];

    // ---- stage W2 (pre-swizzled: straight b128 copy) ----
    #pragma unroll
    for (int i = 0; i < 4; ++i) {
        int f = t + i * 256;
        *(uint4*)&sW2[f * 8] = *(const uint4*)&w2s[f * 8];
    }
    if (t < 128) { sB2s[t] = b2[t]; sWhs[t] = Wh[t]; }
    float bh0 = bh[0];

    // ---- identity B-fragments (registers, built once) ----
    // I_lo: B[k][n] = (k==n), k=qq*8+j, n=m  -> 1.0bf16 where qq*8+j == m
    // I_hi: B[k][n] = (k==16+n)              -> 1.0bf16 where qq*8+j == 16+m
    B8U Ilo, Ihi;
    {
        uint lo[4], hi[4];
        #pragma unroll
        for (int p = 0; p < 4; ++p) {
            int k0 = q8 + 2 * p;
            lo[p] = ((k0 == m) ? 0x3f80u : 0u) | ((k0 + 1 == m) ? 0x3f800000u : 0u);
            hi[p] = ((k0 == 16 + m) ? 0x3f80u : 0u) | ((k0 + 1 == 16 + m) ? 0x3f800000u : 0u);
        }
        Ilo.u = make_uint4(lo[0], lo[1], lo[2], lo[3]);
        Ihi.u = make_uint4(hi[0], hi[1], hi[2], hi[3]);
    }

    // ---- pack X A-fragments ----
    B8U a0, a1;
    a0.u = make_uint4(pack2(x0.x, x0.y), pack2(x0.z, x0.w),
                      pack2(x1.x, x1.y), pack2(x1.z, x1.w));
    a1.u = make_uint4(pack2(x2.x, x2.y), pack2(x2.z, x2.w),
                      pack2(x3.x, x3.y), pack2(x3.z, x3.w));

    __syncthreads();   // protects sW2/biases only; sH is wave-local

    // ---- h1 = X@Wr' + qc@I + nh@I + nt@I   (all inside MFMA accumulators) ----
    f32x4 acc1[4];
    #pragma unroll
    for (int nt = 0; nt < 4; ++nt) {
        const ushort* row = &wrtb[(nt * 16 + m) * 64];
        B8U b0, b1v;
        b0.u  = *(const uint4*)&row[q8];
        b1v.u = *(const uint4*)&row[32 + q8];
        f32x4 c = {0.f, 0.f, 0.f, 0.f};
        c = __builtin_amdgcn_mfma_f32_16x16x32_bf16(a0.b, b0.b, c, 0, 0, 0);
        c = __builtin_amdgcn_mfma_f32_16x16x32_bf16(a1.b, b1v.b, c, 0, 0, 0);
        acc1[nt] = c;
    }
    // gather adds: cols nt*16+n come from K-slice nt*16..nt*16+15 of each table
    acc1[0] = __builtin_amdgcn_mfma_f32_16x16x32_bf16(gq0.b, Ilo.b, acc1[0], 0, 0, 0);
    acc1[0] = __builtin_amdgcn_mfma_f32_16x16x32_bf16(gh0.b, Ilo.b, acc1[0], 0, 0, 0);
    acc1[0] = __builtin_amdgcn_mfma_f32_16x16x32_bf16(gt0.b, Ilo.b, acc1[0], 0, 0, 0);
    acc1[1] = __builtin_amdgcn_mfma_f32_16x16x32_bf16(gq0.b, Ihi.b, acc1[1], 0, 0, 0);
    acc1[1] = __builtin_amdgcn_mfma_f32_16x16x32_bf16(gh0.b, Ihi.b, acc1[1], 0, 0, 0);
    acc1[1] = __builtin_amdgcn_mfma_f32_16x16x32_bf16(gt0.b, Ihi.b, acc1[1], 0, 0, 0);
    acc1[2] = __builtin_amdgcn_mfma_f32_16x16x32_bf16(gq1.b, Ilo.b, acc1[2], 0, 0, 0);
    acc1[2] = __builtin_amdgcn_mfma_f32_16x16x32_bf16(gh1.b, Ilo.b, acc1[2], 0, 0, 0);
    acc1[2] = __builtin_amdgcn_mfma_f32_16x16x32_bf16(gt1.b, Ilo.b, acc1[2], 0, 0, 0);
    acc1[3] = __builtin_amdgcn_mfma_f32_16x16x32_bf16(gq1.b, Ihi.b, acc1[3], 0, 0, 0);
    acc1[3] = __builtin_amdgcn_mfma_f32_16x16x32_bf16(gh1.b, Ihi.b, acc1[3], 0, 0, 0);
    acc1[3] = __builtin_amdgcn_mfma_f32_16x16x32_bf16(gt1.b, Ihi.b, acc1[3], 0, 0, 0);

    // ---- epilogue: relu, pack, write H1 (perm cols: phys = m*4 + nt) ----
    #pragma unroll
    for (int r = 0; r < 4; ++r) {
        int e = w * 16 + qq * 4 + r;
        uint lo = pack2(fmaxf(acc1[0][r], 0.f), fmaxf(acc1[1][r], 0.f));
        uint hi = pack2(fmaxf(acc1[2][r], 0.f), fmaxf(acc1[3][r], 0.f));
        *(uint2*)&sH[e * 72 + m * 4] = make_uint2(lo, hi);
    }

    // ---- h2 = relu(H1@W2 + b2); logit = h2@Wh + bh ----
    bf16x8 A0 = *(const bf16x8*)&sH[(w * 16 + m) * 72 + q8];
    bf16x8 A1 = *(const bf16x8*)&sH[(w * 16 + m) * 72 + 32 + q8];
    const int o1 = (qq ^ (m & 7)) * 8;
    const int o2 = o1 ^ 32;
    float part[4] = {0.f, 0.f, 0.f, 0.f};
    #pragma unroll
    for (int nt = 0; nt < 8; ++nt) {
        B8U B0, B1;
        B0.u = *(const uint4*)&sW2[nt * 1024 + m * 64 + o1];
        B1.u = *(const uint4*)&sW2[nt * 1024 + m * 64 + o2];
        f32x4 c = {0.f, 0.f, 0.f, 0.f};
        c = __builtin_amdgcn_mfma_f32_16x16x32_bf16(A0, B0.b, c, 0, 0, 0);
        c = __builtin_amdgcn_mfma_f32_16x16x32_bf16(A1, B1.b, c, 0, 0, 0);
        int col = nt * 16 + m;
        float b2v = sB2s[col], whv = sWhs[col];
        #pragma unroll
        for (int r = 0; r < 4; ++r)
            part[r] = fmaf(fmaxf(c[r] + b2v, 0.f), whv, part[r]);
    }

    // ---- 16-lane reduction on the VALU pipe (DPP row_ror) ----
    part[0] = row16_reduce(part[0]);
    part[1] = row16_reduce(part[1]);
    part[2] = row16_reduce(part[2]);
    part[3] = row16_reduce(part[3]);

    if (m == 0) {
        float4 o;
        o.x = 1.f / (1.f + __expf(-(part[0] + bh0)));
        o.y = 1.f / (1.f + __expf(-(part[1] + bh0)));
        o.z = 1.f / (1.f + __expf(-(part[2] + bh0)));
        o.w = 1.f / (1.f + __expf(-(part[3] + bh0)));
        *(float4*)&out[ebase + w * 16 + qq * 4] = o;
    }
}

extern "C" void kernel_launch(void* const* d_in, const int* in_sizes, int n_in,
                              void* d_out, int out_size, void* d_ws, size_t ws_size,
                              hipStream_t stream)
{
    const float* Q   = (const float*)d_in[0];
    const float* Xn  = (const float*)d_in[1];
    const float* Xe  = (const float*)d_in[2];
    const int*   EI  = (const int*)d_in[3];
    const int*   NB  = (const int*)d_in[4];
    const float* Wq  = (const float*)d_in[5];
    const float* bq  = (const float*)d_in[6];
    const float* We  = (const float*)d_in[7];
    const float* be  = (const float*)d_in[8];
    const float* Wr  = (const float*)d_in[9];
    const float* br  = (const float*)d_in[10];
    const float* W1  = (const float*)d_in[11];
    const float* b1  = (const float*)d_in[12];
    const float* W2  = (const float*)d_in[13];
    const float* b2  = (const float*)d_in[14];
    const float* Wh  = (const float*)d_in[15];
    const float* bh  = (const float*)d_in[16];
    float* out = (float*)d_out;
    char*  wsb = (char*)d_ws;

    prep_a<<<5 + (NEDGE + 1023) / 1024, 256, 0, stream>>>(
        Q, Wq, bq, We, be, Wr, br, W1, b1, W2, EI, NB, wsb);
    prep_nodes<<<(NNODE + 63) / 64, 256, 0, stream>>>(Xn, wsb, wsb);
    edge_kernel<<<NEDGE / 64, 256, 0, stream>>>(Xe, b2, Wh, bh, wsb, out);
}